// Round 14
// baseline (85.767 us; speedup 1.0000x reference)
//
#include <hip/hip_runtime.h>

#define N_STATE 512
#define N_HEAD 8
#define HEAD_DIM 64
#define KV_LEN 32768
#define T_TOTAL 32769

typedef float v4f __attribute__((ext_vector_type(4)));

// d_out layout (float offsets)
#define QK_OFF 512
#define K_OFF (512 + N_HEAD * T_TOTAL)
#define V_OFF (K_OFF + (size_t)T_TOTAL * N_STATE)

// d_ws layout (float offsets)
#define WS_Q 0
#define WS_K 512
#define WS_V 1024
#define WS_WV 1600       // 512: attention output (pre out-proj)
#define WS_PL 6272       // NBLK*8 per-block sumexp
#define WS_PART 14848    // NBLK*512 partial acc, then RB2*512 part2
#define NBLK 1024
#define RPB 32           // rows per block
#define NCH 8            // chunks per block (RPB/4)
#define RB2 32

// ---------------------------------------------------------------------------
// Kernel A: q = x@wq.T + bq ; k_new = x@wk.T ; v_new = x@wv.T + bv
// ---------------------------------------------------------------------------
__global__ void proj_kernel(const float* __restrict__ x,
                            const float* __restrict__ wq, const float* __restrict__ bq,
                            const float* __restrict__ wk,
                            const float* __restrict__ wv, const float* __restrict__ bv,
                            float* __restrict__ ws, float* __restrict__ out)
{
    int o = blockIdx.x * 256 + threadIdx.x;      // 0..1535
    int which = o >> 9;
    int idx   = o & 511;
    const float* W = (which == 0) ? wq : (which == 1) ? wk : wv;
    const float4* Wr = (const float4*)(W + (size_t)idx * N_STATE);
    const float4* xv = (const float4*)x;
    float s = 0.f;
#pragma unroll 8
    for (int j = 0; j < N_STATE / 4; ++j) {
        float4 a = xv[j], b = Wr[j];
        s += a.x * b.x + a.y * b.y + a.z * b.z + a.w * b.w;
    }
    if (which == 0) {
        s += bq[idx];
        ws[WS_Q + idx] = s;
    } else if (which == 1) {
        ws[WS_K + idx] = s;
        out[K_OFF + (size_t)KV_LEN * N_STATE + idx] = s;   // new k row
    } else {
        s += bv[idx];
        ws[WS_V + idx] = s;
        out[V_OFF + (size_t)KV_LEN * N_STATE + idx] = s;   // new v row
    }
}

// ---------------------------------------------------------------------------
// Kernel B (fused stream): DEEP-MLP variant.  All 16 loads (8 K-f4 + 8 V-f4
// per thread, 64 VGPRs of payload) are issued BACK-TO-BACK before any
// dependent consume, so each wave presents 16 concurrent HBM requests
// instead of the 2-4 every previous variant managed (depth-1 prefetch /
// load-store chains).  Reads are the latency-bound direction (writes are
// fire-and-forget: fill=7.1 TB/s; every read-involving variant = 2.6-3.5);
// this is the one untested mechanism that explains that split.
// Stores/compute consume in order afterwards.  Epilogue as before.
// ---------------------------------------------------------------------------
__global__ void __launch_bounds__(512)
stream_kernel(const float* __restrict__ kc, const float* __restrict__ vc,
              const float* __restrict__ ws_ro,
              float* __restrict__ out,
              float* __restrict__ part, float* __restrict__ pl)
{
    int tid = threadIdx.x;
    int i   = tid & 127;       // float4 column index (0..127)
    int rg  = tid >> 7;        // row group (0..3)
    int h   = i >> 4;          // head (0..7)
    v4f q4 = ((const v4f*)(ws_ro + WS_Q))[i];
    q4 *= 0.125f;              // scale^2
    const v4f* kc4 = (const v4f*)kc;
    const v4f* vc4 = (const v4f*)vc;
    v4f* kout4 = (v4f*)(out + K_OFF);
    v4f* vout4 = (v4f*)(out + V_OFF);
    float* qkout = out + QK_OFF;

    size_t cb = (size_t)blockIdx.x * RPB * 128;

    v4f karr[NCH], varr[NCH];
    // ---- issue ALL loads back-to-back: 16 outstanding per wave ----
#pragma unroll
    for (int n = 0; n < NCH; ++n)
        karr[n] = kc4[cb + (size_t)n * 512 + tid];
#pragma unroll
    for (int n = 0; n < NCH; ++n)
        varr[n] = vc4[cb + (size_t)n * 512 + tid];

    float l = 0.f;
    v4f acc = (v4f)0.f;
    float parr[NCH];
    // ---- consume in order: store + logit + weighted accumulate ----
#pragma unroll
    for (int n = 0; n < NCH; ++n) {
        kout4[cb + (size_t)n * 512 + tid] = karr[n];
        vout4[cb + (size_t)n * 512 + tid] = varr[n];
        float p = karr[n].x * q4.x + karr[n].y * q4.y
                + karr[n].z * q4.z + karr[n].w * q4.w;
        p += __shfl_xor(p, 1);
        p += __shfl_xor(p, 2);
        p += __shfl_xor(p, 4);
        p += __shfl_xor(p, 8);
        parr[n] = p;
        float w = __expf(p);
        l += w;
        acc += w * varr[n];
    }

    // ---- epilogue: coalesced qk flush + partial merge (single barrier) ----
    __shared__ float qks[N_HEAD][RPB];
    __shared__ v4f sacc[3][128];
    __shared__ float sl[3][8];
    if ((tid & 15) == 0) {                       // one thread per (rg, h)
#pragma unroll
        for (int n = 0; n < NCH; ++n) qks[h][n * 4 + rg] = parr[n];
        if (rg != 0) sl[rg - 1][h] = l;
    }
    if (rg != 0) sacc[rg - 1][i] = acc;
    __syncthreads();

    int base = blockIdx.x * RPB;
    if (tid < N_HEAD * RPB) {                    // 256 threads: 8 heads x 32 rows
        int hh = tid >> 5, tt = tid & (RPB - 1);
        qkout[(size_t)hh * T_TOTAL + base + tt] = qks[hh][tt];
    }
    if (rg == 0) {
#pragma unroll
        for (int r = 0; r < 3; ++r) acc += sacc[r][i];
        ((v4f*)(part + (size_t)blockIdx.x * N_STATE))[i] = acc;
        if ((tid & 15) == 0)
            pl[blockIdx.x * N_HEAD + h] = l + sl[0][h] + sl[1][h] + sl[2][h];
    }
}

// ---------------------------------------------------------------------------
// Kernel C: fold NBLK acc rows -> RB2 rows (pure sum, coalesced float4).
// ---------------------------------------------------------------------------
__global__ void reduce1_kernel(const float* __restrict__ part,
                               float* __restrict__ part2, int rpb)
{
    int c4 = threadIdx.x & 127;
    int rg = threadIdx.x >> 7;
    int hrpb = rpb >> 1;
    int r0 = blockIdx.x * rpb + rg * hrpb;
    float4 acc = {0.f, 0.f, 0.f, 0.f};
    for (int r = 0; r < hrpb; ++r) {
        float4 p = ((const float4*)(part + (size_t)(r0 + r) * N_STATE))[c4];
        acc.x += p.x; acc.y += p.y; acc.z += p.z; acc.w += p.w;
    }
    __shared__ float4 sacc[128];
    if (rg == 1) sacc[c4] = acc;
    __syncthreads();
    if (rg == 0) {
        float4 o = sacc[c4];
        acc.x += o.x; acc.y += o.y; acc.z += o.z; acc.w += o.w;
        ((float4*)(part2 + (size_t)blockIdx.x * N_STATE))[c4] = acc;
    }
}

// ---------------------------------------------------------------------------
// Kernel D (fused mstats + reduce2): ONE block x 512 threads.
// ---------------------------------------------------------------------------
__global__ void mstats2_kernel(float* __restrict__ ws, float* __restrict__ out,
                               const float* __restrict__ part2, int nblk)
{
    int tid = threadIdx.x;
    int h   = tid >> 6;       // 0..7 (== wave index)
    int j   = tid & 63;
    const float* pl = ws + WS_PL;
    __shared__ float slf[8], swn[8];

    float lg = 0.f;
    for (int b = j; b < nblk; b += 64) lg += pl[b * N_HEAD + h];
    for (int off = 32; off >= 1; off >>= 1) lg += __shfl_xor(lg, off);

    float p = ws[WS_Q + h * 64 + j] * ws[WS_K + h * 64 + j];
    for (int off = 32; off >= 1; off >>= 1) p += __shfl_xor(p, off);
    p *= 0.125f;

    if (j == 0) {
        float wn = __expf(p);
        out[QK_OFF + (size_t)h * T_TOTAL + KV_LEN] = p;
        slf[h] = lg + wn;
        swn[h] = wn;
    }
    __syncthreads();

    // reduce2: column c = tid
    int c = tid;
    float s = 0.f;
#pragma unroll
    for (int b = 0; b < RB2; ++b) s += part2[(size_t)b * N_STATE + c];
    s += swn[c >> 6] * ws[WS_V + c];
    ws[WS_WV + c] = s / slf[c >> 6];
}

// ---------------------------------------------------------------------------
// Kernel E: out = wv_ @ wo.T + bo. 32 blocks x 256 threads (16 outputs/blk).
// ---------------------------------------------------------------------------
__global__ void outproj_kernel(const float* __restrict__ ws, const float* __restrict__ wo,
                               const float* __restrict__ bo, float* __restrict__ out)
{
    int r    = blockIdx.x * 16 + (threadIdx.x >> 4);
    int lane = threadIdx.x & 15;
    const float4* wr  = (const float4*)(wo + (size_t)r * N_STATE);
    const float4* wv4 = (const float4*)(ws + WS_WV);
    float s = 0.f;
#pragma unroll
    for (int k = 0; k < 8; ++k) {
        int c4 = lane + k * 16;
        float4 a = wv4[c4], b = wr[c4];
        s += a.x * b.x + a.y * b.y + a.z * b.z + a.w * b.w;
    }
    s += __shfl_xor(s, 1);
    s += __shfl_xor(s, 2);
    s += __shfl_xor(s, 4);
    s += __shfl_xor(s, 8);
    if (lane == 0) out[r] = s + bo[r];
}

extern "C" void kernel_launch(void* const* d_in, const int* in_sizes, int n_in,
                              void* d_out, int out_size, void* d_ws, size_t ws_size,
                              hipStream_t stream)
{
    const float* x  = (const float*)d_in[0];
    const float* kc = (const float*)d_in[1];
    const float* vc = (const float*)d_in[2];
    const float* wq = (const float*)d_in[3];
    const float* bq = (const float*)d_in[4];
    const float* wk = (const float*)d_in[5];
    const float* wv = (const float*)d_in[6];
    const float* bv = (const float*)d_in[7];
    const float* wo = (const float*)d_in[8];
    const float* bo = (const float*)d_in[9];
    float* out = (float*)d_out;
    float* ws  = (float*)d_ws;

    float* part  = ws + WS_PART;
    float* part2 = part + (size_t)NBLK * N_STATE;
    float* pl    = ws + WS_PL;

    hipLaunchKernelGGL(proj_kernel, dim3(6), dim3(256), 0, stream,
                       x, wq, bq, wk, wv, bv, ws, out);
    hipLaunchKernelGGL(stream_kernel, dim3(NBLK), dim3(512), 0, stream,
                       kc, vc, ws, out, part, pl);
    hipLaunchKernelGGL(reduce1_kernel, dim3(RB2), dim3(256), 0, stream,
                       part, part2, NBLK / RB2);
    hipLaunchKernelGGL(mstats2_kernel, dim3(1), dim3(512), 0, stream,
                       ws, out, part2, NBLK);
    hipLaunchKernelGGL(outproj_kernel, dim3(32), dim3(256), 0, stream, ws, wo, bo, out);
}